// Round 1
// baseline (292.730 us; speedup 1.0000x reference)
//
#include <hip/hip_runtime.h>

#define T_  32
#define B_  32
#define S_  128
#define N_  8
#define A_  10
#define E_  64
#define SS_ 32
#define BT_ (T_*B_)

__device__ __forceinline__ unsigned rotl32(unsigned v, int n){ return (v<<n)|(v>>(32-n)); }

// Threefry-2x32, 20 rounds, standard JAX constants.
__device__ __forceinline__ void threefry2x32(unsigned k0, unsigned k1,
                                             unsigned x0, unsigned x1,
                                             unsigned &o0, unsigned &o1){
  const unsigned ks2 = k0 ^ k1 ^ 0x1BD11BDAu;
  x0 += k0; x1 += k1;
  x0+=x1; x1=rotl32(x1,13); x1^=x0;
  x0+=x1; x1=rotl32(x1,15); x1^=x0;
  x0+=x1; x1=rotl32(x1,26); x1^=x0;
  x0+=x1; x1=rotl32(x1, 6); x1^=x0;
  x0+=k1; x1+=ks2+1u;
  x0+=x1; x1=rotl32(x1,17); x1^=x0;
  x0+=x1; x1=rotl32(x1,29); x1^=x0;
  x0+=x1; x1=rotl32(x1,16); x1^=x0;
  x0+=x1; x1=rotl32(x1,24); x1^=x0;
  x0+=ks2; x1+=k0+2u;
  x0+=x1; x1=rotl32(x1,13); x1^=x0;
  x0+=x1; x1=rotl32(x1,15); x1^=x0;
  x0+=x1; x1=rotl32(x1,26); x1^=x0;
  x0+=x1; x1=rotl32(x1, 6); x1^=x0;
  x0+=k0; x1+=k1+3u;
  x0+=x1; x1=rotl32(x1,17); x1^=x0;
  x0+=x1; x1=rotl32(x1,29); x1^=x0;
  x0+=x1; x1=rotl32(x1,16); x1^=x0;
  x0+=x1; x1=rotl32(x1,24); x1^=x0;
  x0+=k1; x1+=ks2+4u;
  x0+=x1; x1=rotl32(x1,13); x1^=x0;
  x0+=x1; x1=rotl32(x1,15); x1^=x0;
  x0+=x1; x1=rotl32(x1,26); x1^=x0;
  x0+=x1; x1=rotl32(x1, 6); x1^=x0;
  x0+=ks2; x1+=k0+5u;
  o0=x0; o1=x1;
}

__global__ __launch_bounds__(256) void shapley_kernel(
    const float* __restrict__ states,    // (BT,128)
    const float* __restrict__ agent_qs,  // (BT,A=10,N=8)  [original (T,B,A,N)]
    const float* __restrict__ W1,        // (208,64)
    const float* __restrict__ b1,        // (64)
    const float* __restrict__ W2,        // (64,64)
    const float* __restrict__ b2,        // (64)
    const float* __restrict__ Wa,        // (64,1)
    const float* __restrict__ ba,        // (1)
    const float* __restrict__ Wv1,       // (128,64)
    const float* __restrict__ bv1,       // (64)
    const float* __restrict__ Wv2,       // (64,1)
    const float* __restrict__ bv2,       // (1)
    const int*   __restrict__ rng,       // (1)
    float* __restrict__ out)             // (BT,8)
{
  __shared__ float W1q_l[A_*N_*E_];   // 80*64 = 20 KB
  __shared__ float W2_l[E_*E_];       // 64*64 = 16 KB
  __shared__ float spb_l[E_];         // state@W1s + b1
  __shared__ float b2_l[E_];
  __shared__ float Wa_l[E_];
  __shared__ float outacc[4][N_];
  __shared__ float v_l;

  const int bt   = blockIdx.x;
  const int tid  = threadIdx.x;
  const int w    = tid >> 6;
  const int lane = tid & 63;

  // cooperative staging of weights
  for (int i = tid; i < A_*N_*E_; i += 256) W1q_l[i] = W1[S_*E_ + i];
  for (int i = tid; i < E_*E_;    i += 256) W2_l[i]  = W2[i];
  if (tid < E_) { b2_l[tid] = b2[tid]; Wa_l[tid] = Wa[tid]; }

  // wave 0: per-bt state projection and value head
  if (w == 0) {
    float sacc = b1[lane];
    float vacc = bv1[lane];
    const float* st = states + bt*S_;
    #pragma unroll 8
    for (int k = 0; k < S_; ++k) {
      float sv = st[k];
      sacc = fmaf(sv, W1 [k*E_ + lane], sacc);
      vacc = fmaf(sv, Wv1[k*E_ + lane], vacc);
    }
    spb_l[lane] = sacc;
    float pv = fmaxf(vacc, 0.f) * Wv2[lane];
    #pragma unroll
    for (int off = 32; off >= 1; off >>= 1) pv += __shfl_xor(pv, off, 64);
    if (lane == 0) v_l = pv + bv2[0];
  }
  __syncthreads();

  const unsigned k0 = 0u;                    // hi word of seed (int32 seed -> 0)
  const unsigned k1 = (unsigned)rng[0];      // lo word
  const float vba = v_l + ba[0];
  float agacc = 0.f;                         // lane n<8: running sum for agent n

  for (int si = 0; si < SS_/4; ++si) {
    const int s = w + 4*si;
    // --- partitionable threefry: counter = flat index (hi=0, lo=i); bits = o0^o1
    unsigned cnt = (unsigned)(((bt*SS_ + s) << 3) + (lane & 7));
    unsigned o0, o1;
    threefry2x32(k0, k1, 0u, cnt, o0, o1);
    unsigned key23 = (o0 ^ o1) >> 9;        // monotone in uniform float value
    unsigned kv[8];
    #pragma unroll
    for (int j = 0; j < 8; ++j) kv[j] = __shfl(key23, j, 64);

    // stable ascending argsort (selection, strict < keeps lowest index on ties)
    int p2a[8]; unsigned used = 0;
    #pragma unroll
    for (int p = 0; p < 8; ++p) {
      unsigned bv = 0xFFFFFFFFu; int best = 0;
      #pragma unroll
      for (int j = 0; j < 8; ++j) {
        bool ok = (((used >> j) & 1u) == 0u) && (kv[j] < bv);
        if (ok) { bv = kv[j]; best = j; }
      }
      p2a[p] = best; used |= (1u << best);
    }

    // prefix-coalition MLP; lane = embedding channel
    float acc = 0.f;
    const float* aqb = agent_qs + bt*(A_*N_);
    #pragma unroll
    for (int p = 0; p < 8; ++p) {
      const int g = p2a[p];
      #pragma unroll
      for (int a = 0; a < A_; ++a)
        acc = fmaf(aqb[a*N_ + g], W1q_l[(p*A_ + a)*E_ + lane], acc);
      float h1 = fmaxf(acc + spb_l[lane], 0.f);

      float h2a = b2_l[lane];
      #pragma unroll 16
      for (int e = 0; e < E_; ++e) {
        float h1e = __shfl(h1, e, 64);
        h2a = fmaf(h1e, W2_l[e*E_ + lane], h2a);
      }
      float h2 = fmaxf(h2a, 0.f);
      float part = h2 * Wa_l[lane];
      #pragma unroll
      for (int off = 32; off >= 1; off >>= 1) part += __shfl_xor(part, off, 64);
      float contrib = part + vba;
      if (lane == g) agacc += contrib;      // one contrib per agent per sample
    }
  }

  if (lane < N_) outacc[w][lane] = agacc;
  __syncthreads();
  if (tid < N_) {
    float r = (outacc[0][tid] + outacc[1][tid] + outacc[2][tid] + outacc[3][tid]) * (1.f/SS_);
    out[bt*N_ + tid] = r;
  }
}

extern "C" void kernel_launch(void* const* d_in, const int* in_sizes, int n_in,
                              void* d_out, int out_size, void* d_ws, size_t ws_size,
                              hipStream_t stream) {
  const float* states   = (const float*)d_in[0];
  const float* agent_qs = (const float*)d_in[1];
  const float* W1  = (const float*)d_in[2];
  const float* b1  = (const float*)d_in[3];
  const float* W2  = (const float*)d_in[4];
  const float* b2  = (const float*)d_in[5];
  const float* Wa  = (const float*)d_in[6];
  const float* ba  = (const float*)d_in[7];
  const float* Wv1 = (const float*)d_in[8];
  const float* bv1 = (const float*)d_in[9];
  const float* Wv2 = (const float*)d_in[10];
  const float* bv2 = (const float*)d_in[11];
  const int*   rng = (const int*)d_in[12];
  float* out = (float*)d_out;

  hipLaunchKernelGGL(shapley_kernel, dim3(BT_), dim3(256), 0, stream,
                     states, agent_qs, W1, b1, W2, b2, Wa, ba, Wv1, bv1, Wv2, bv2,
                     rng, out);
}

// Round 3
// 90.437 us; speedup vs baseline: 3.2369x; 3.2369x over previous
//
// Round 3 = round 2 kernel resubmitted verbatim (round 2 died to UnresponsiveContainer
// before any measurement; no data to act on).
#include <hip/hip_runtime.h>

#define S_ 128
#define N_ 8
#define A_ 10
#define E_ 64
#define SS_ 32
#define BT_ 1024

__device__ __forceinline__ unsigned rotl32(unsigned v, int n){ return (v<<n)|(v>>(32-n)); }

// Threefry-2x32, 20 rounds, standard JAX constants. (Verified bit-exact round 1.)
__device__ __forceinline__ void threefry2x32(unsigned k0, unsigned k1,
                                             unsigned x0, unsigned x1,
                                             unsigned &o0, unsigned &o1){
  const unsigned ks2 = k0 ^ k1 ^ 0x1BD11BDAu;
  x0 += k0; x1 += k1;
  x0+=x1; x1=rotl32(x1,13); x1^=x0;
  x0+=x1; x1=rotl32(x1,15); x1^=x0;
  x0+=x1; x1=rotl32(x1,26); x1^=x0;
  x0+=x1; x1=rotl32(x1, 6); x1^=x0;
  x0+=k1; x1+=ks2+1u;
  x0+=x1; x1=rotl32(x1,17); x1^=x0;
  x0+=x1; x1=rotl32(x1,29); x1^=x0;
  x0+=x1; x1=rotl32(x1,16); x1^=x0;
  x0+=x1; x1=rotl32(x1,24); x1^=x0;
  x0+=ks2; x1+=k0+2u;
  x0+=x1; x1=rotl32(x1,13); x1^=x0;
  x0+=x1; x1=rotl32(x1,15); x1^=x0;
  x0+=x1; x1=rotl32(x1,26); x1^=x0;
  x0+=x1; x1=rotl32(x1, 6); x1^=x0;
  x0+=k0; x1+=k1+3u;
  x0+=x1; x1=rotl32(x1,17); x1^=x0;
  x0+=x1; x1=rotl32(x1,29); x1^=x0;
  x0+=x1; x1=rotl32(x1,16); x1^=x0;
  x0+=x1; x1=rotl32(x1,24); x1^=x0;
  x0+=k1; x1+=ks2+4u;
  x0+=x1; x1=rotl32(x1,13); x1^=x0;
  x0+=x1; x1=rotl32(x1,15); x1^=x0;
  x0+=x1; x1=rotl32(x1,26); x1^=x0;
  x0+=x1; x1=rotl32(x1, 6); x1^=x0;
  x0+=ks2; x1+=k0+5u;
  o0=x0; o1=x1;
}

__device__ __forceinline__ float rl_f32(float v, int lane){
  return __int_as_float(__builtin_amdgcn_readlane(__float_as_int(v), lane));
}

__global__ __launch_bounds__(256) void shapley_kernel(
    const float* __restrict__ states,    // (BT,128)
    const float* __restrict__ agent_qs,  // (BT,A=10,N=8)
    const float* __restrict__ W1,        // (208,64)
    const float* __restrict__ b1,        // (64)
    const float* __restrict__ W2,        // (64,64)
    const float* __restrict__ b2,        // (64)
    const float* __restrict__ Wa,        // (64,1)
    const float* __restrict__ ba,        // (1)
    const float* __restrict__ Wv1,       // (128,64)
    const float* __restrict__ bv1,       // (64)
    const float* __restrict__ Wv2,       // (64,1)
    const float* __restrict__ bv2,       // (1)
    const int*   __restrict__ rng,       // (1)
    float* __restrict__ out)             // (BT,8)
{
  __shared__ float c_l[N_*N_*E_];     // c[p][g][e]  16 KB
  __shared__ float ag_l[4*N_*E_];     // per-wave per-agent lane partials, 8 KB
  __shared__ float spb_l[E_];         // state@W1s + b1
  __shared__ float v_l;

  const int bt   = blockIdx.x;
  const int tid  = threadIdx.x;
  const int w    = tid >> 6;
  const int lane = tid & 63;

  // zero the agent accumulators
  for (int i = tid; i < 4*N_*E_; i += 256) ag_l[i] = 0.f;

  // --- cooperative c-table: c[p][g][lane] = sum_a aq[a,g] * W1q[p,a,lane]
  {
    const float* aqb = agent_qs + bt*(A_*N_);
    #pragma unroll
    for (int i = 0; i < 16; ++i) {
      const int combo = w*16 + i;
      const int p = combo >> 3, g = combo & 7;
      float acc = 0.f;
      #pragma unroll
      for (int a = 0; a < A_; ++a)
        acc = fmaf(aqb[a*N_ + g], W1[(S_ + p*A_ + a)*E_ + lane], acc);
      c_l[combo*E_ + lane] = acc;
    }
  }

  // --- wave 0: state projection + value head
  if (w == 0) {
    float sacc = b1[lane];
    float vacc = bv1[lane];
    const float* st = states + bt*S_;
    #pragma unroll 8
    for (int k = 0; k < S_; ++k) {
      float sv = st[k];
      sacc = fmaf(sv, W1 [k*E_ + lane], sacc);
      vacc = fmaf(sv, Wv1[k*E_ + lane], vacc);
    }
    spb_l[lane] = sacc;
    float pv = fmaxf(vacc, 0.f) * Wv2[lane];
    #pragma unroll
    for (int off = 32; off >= 1; off >>= 1) pv += __shfl_xor(pv, off, 64);
    if (lane == 0) v_l = pv + bv2[0];
  }

  // --- per-lane register-resident weights
  float w2c[E_];                      // W2 column `lane`: w2c[e] = W2[e][lane]
  #pragma unroll
  for (int e = 0; e < E_; ++e) w2c[e] = W2[e*E_ + lane];
  const float b2v = b2[lane];
  const float wav = Wa[lane];

  __syncthreads();
  const float spb = spb_l[lane];
  const float vba = v_l + ba[0];

  // --- one threefry call covers this wave's 8 samples: lane = (si, j)
  const unsigned k1 = (unsigned)rng[0];
  unsigned cnt = (unsigned)(((bt*SS_ + w + 4*(lane >> 3)) << 3) + (lane & 7));
  unsigned o0, o1;
  threefry2x32(0u, k1, 0u, cnt, o0, o1);
  const unsigned comp = (((o0 ^ o1) >> 9) << 3) | (unsigned)(lane & 7); // 26-bit, stable tiebreak

  for (int si = 0; si < 8; ++si) {
    // fetch this sample's 8 composite keys (uniform scalars)
    unsigned cj[8];
    #pragma unroll
    for (int j = 0; j < 8; ++j)
      cj[j] = (unsigned)__builtin_amdgcn_readlane((int)comp, si*8 + j);

    // rank-based stable argsort (shallow, no serial min-extraction)
    int rnk[8] = {0,0,0,0,0,0,0,0};
    #pragma unroll
    for (int j = 0; j < 8; ++j)
      #pragma unroll
      for (int jp = j+1; jp < 8; ++jp) {
        int b = (cj[j] < cj[jp]) ? 1 : 0;
        rnk[jp] += b; rnk[j] += 1 - b;
      }
    int p2a[8];
    #pragma unroll
    for (int p = 0; p < 8; ++p) {
      int g = 0;
      #pragma unroll
      for (int j = 1; j < 8; ++j) g += (rnk[j] == p) ? j : 0;
      p2a[p] = g;
    }

    float acc = 0.f;
    #pragma unroll
    for (int p = 0; p < 8; ++p) {
      const int g = p2a[p];
      const float qc = c_l[((p << 3) + g)*E_ + lane];  // layer-1 increment
      acc += qc;
      const float h1 = fmaxf(acc + spb, 0.f);

      // h2[lane] = relu( sum_e h1[e] * W2[e][lane] + b2[lane] )
      float a0 = b2v, a1 = 0.f, a2 = 0.f, a3 = 0.f;
      #pragma unroll
      for (int e = 0; e < E_; e += 4) {
        a0 = fmaf(rl_f32(h1, e+0), w2c[e+0], a0);
        a1 = fmaf(rl_f32(h1, e+1), w2c[e+1], a1);
        a2 = fmaf(rl_f32(h1, e+2), w2c[e+2], a2);
        a3 = fmaf(rl_f32(h1, e+3), w2c[e+3], a3);
      }
      const float h2 = fmaxf((a0 + a1) + (a2 + a3), 0.f);
      const float part = h2 * wav;

      ag_l[((w << 3) + g)*E_ + lane] += part;          // route to agent g
    }
  }

  __syncthreads();
  if (w == 0) {
    #pragma unroll
    for (int n = 0; n < N_; ++n) {
      float s = ag_l[(0*N_ + n)*E_ + lane] + ag_l[(1*N_ + n)*E_ + lane]
              + ag_l[(2*N_ + n)*E_ + lane] + ag_l[(3*N_ + n)*E_ + lane];
      #pragma unroll
      for (int off = 32; off >= 1; off >>= 1) s += __shfl_xor(s, off, 64);
      if (lane == 0) out[bt*N_ + n] = s*(1.f/SS_) + vba;
    }
  }
}

extern "C" void kernel_launch(void* const* d_in, const int* in_sizes, int n_in,
                              void* d_out, int out_size, void* d_ws, size_t ws_size,
                              hipStream_t stream) {
  const float* states   = (const float*)d_in[0];
  const float* agent_qs = (const float*)d_in[1];
  const float* W1  = (const float*)d_in[2];
  const float* b1  = (const float*)d_in[3];
  const float* W2  = (const float*)d_in[4];
  const float* b2  = (const float*)d_in[5];
  const float* Wa  = (const float*)d_in[6];
  const float* ba  = (const float*)d_in[7];
  const float* Wv1 = (const float*)d_in[8];
  const float* bv1 = (const float*)d_in[9];
  const float* Wv2 = (const float*)d_in[10];
  const float* bv2 = (const float*)d_in[11];
  const int*   rng = (const int*)d_in[12];
  float* out = (float*)d_out;

  hipLaunchKernelGGL(shapley_kernel, dim3(BT_), dim3(256), 0, stream,
                     states, agent_qs, W1, b1, W2, b2, Wa, ba, Wv1, bv1, Wv2, bv2,
                     rng, out);
}

// Round 4
// 30.059 us; speedup vs baseline: 9.7385x; 3.0086x over previous
//
// R4: MFMA rewrite — h2 matvec as per-wave 64x64x64 bf16 GEMM; lane-parallel sort.
// R3 (90us, VALU 75%, VGPR 52): compiler kept W2 in memory, readlane broadcast
// dominated VALU issue. Layer-1/prefix + epilogue remain fp32 for accuracy.
#include <hip/hip_runtime.h>

typedef __bf16 bf16x8 __attribute__((ext_vector_type(8)));
typedef float  f32x4  __attribute__((ext_vector_type(4)));

#define S_ 128
#define N_ 8
#define A_ 10
#define E_ 64
#define SS_ 32
#define BT_ 1024

__device__ __forceinline__ unsigned rotl32(unsigned v, int n){ return (v<<n)|(v>>(32-n)); }

// Threefry-2x32, 20 rounds, standard JAX constants. (Bit-exact, verified R1/R3.)
__device__ __forceinline__ void threefry2x32(unsigned k0, unsigned k1,
                                             unsigned x0, unsigned x1,
                                             unsigned &o0, unsigned &o1){
  const unsigned ks2 = k0 ^ k1 ^ 0x1BD11BDAu;
  x0 += k0; x1 += k1;
  x0+=x1; x1=rotl32(x1,13); x1^=x0;
  x0+=x1; x1=rotl32(x1,15); x1^=x0;
  x0+=x1; x1=rotl32(x1,26); x1^=x0;
  x0+=x1; x1=rotl32(x1, 6); x1^=x0;
  x0+=k1; x1+=ks2+1u;
  x0+=x1; x1=rotl32(x1,17); x1^=x0;
  x0+=x1; x1=rotl32(x1,29); x1^=x0;
  x0+=x1; x1=rotl32(x1,16); x1^=x0;
  x0+=x1; x1=rotl32(x1,24); x1^=x0;
  x0+=ks2; x1+=k0+2u;
  x0+=x1; x1=rotl32(x1,13); x1^=x0;
  x0+=x1; x1=rotl32(x1,15); x1^=x0;
  x0+=x1; x1=rotl32(x1,26); x1^=x0;
  x0+=x1; x1=rotl32(x1, 6); x1^=x0;
  x0+=k0; x1+=k1+3u;
  x0+=x1; x1=rotl32(x1,17); x1^=x0;
  x0+=x1; x1=rotl32(x1,29); x1^=x0;
  x0+=x1; x1=rotl32(x1,16); x1^=x0;
  x0+=x1; x1=rotl32(x1,24); x1^=x0;
  x0+=k1; x1+=ks2+4u;
  x0+=x1; x1=rotl32(x1,13); x1^=x0;
  x0+=x1; x1=rotl32(x1,15); x1^=x0;
  x0+=x1; x1=rotl32(x1,26); x1^=x0;
  x0+=x1; x1=rotl32(x1, 6); x1^=x0;
  x0+=ks2; x1+=k0+5u;
  o0=x0; o1=x1;
}

__global__ __launch_bounds__(256) void shapley_kernel(
    const float* __restrict__ states,    // (BT,128)
    const float* __restrict__ agent_qs,  // (BT,A=10,N=8)
    const float* __restrict__ W1,        // (208,64)
    const float* __restrict__ b1,        // (64)
    const float* __restrict__ W2,        // (64,64)
    const float* __restrict__ b2,        // (64)
    const float* __restrict__ Wa,        // (64,1)
    const float* __restrict__ ba,        // (1)
    const float* __restrict__ Wv1,       // (128,64)
    const float* __restrict__ bv1,       // (64)
    const float* __restrict__ Wv2,       // (64,1)
    const float* __restrict__ bv2,       // (1)
    const int*   __restrict__ rng,       // (1)
    float* __restrict__ out)             // (BT,8)
{
  __shared__ float   c_l[N_*N_*E_];        // c[p][g][e]        16 KB fp32
  __shared__ __bf16  h1_l[4*64*E_];        // per-wave A tiles  32 KB (swizzled)
  __shared__ __bf16  w2_l[E_*E_];          // W2^T [n][k]        8 KB (swizzled)
  __shared__ float   spb_l[E_];            // state@W1s + b1
  __shared__ unsigned char gmap_l[4*64];   // [wave][sample][pos] -> agent
  __shared__ float   contrib_l[4*64];      // [wave][sample][agent]
  __shared__ float   v_l;

  const int bt   = blockIdx.x;
  const int tid  = threadIdx.x;
  const int w    = tid >> 6;
  const int lane = tid & 63;

  // --- c-table: c[p][g][lane] = sum_a aq[a,g] * W1q[p,a,lane]  (fp32, exact)
  {
    const float* aqb = agent_qs + bt*(A_*N_);
    #pragma unroll
    for (int i = 0; i < 16; ++i) {
      const int combo = w*16 + i;
      const int p = combo >> 3, g = combo & 7;
      float acc = 0.f;
      #pragma unroll
      for (int a = 0; a < A_; ++a)
        acc = fmaf(aqb[a*N_ + g], W1[(S_ + p*A_ + a)*E_ + lane], acc);
      c_l[combo*E_ + lane] = acc;
    }
  }

  // --- W2 -> bf16, transposed [n][k], XOR-swizzled rows (one-time)
  {
    const int f = tid & 63;               // output channel n (row of w2_l)
    #pragma unroll
    for (int i = 0; i < 16; ++i) {
      const int e = (tid >> 6) + 4*i;     // input channel k
      const int byte = (f*128 + e*2) ^ ((f & 7) << 4);
      w2_l[byte >> 1] = (__bf16)W2[e*E_ + f];
    }
  }

  // --- wave 0: state projection + value head (fp32)
  if (w == 0) {
    float sacc = b1[lane];
    float vacc = bv1[lane];
    const float* st = states + bt*S_;
    #pragma unroll 8
    for (int k = 0; k < S_; ++k) {
      float sv = st[k];
      sacc = fmaf(sv, W1 [k*E_ + lane], sacc);
      vacc = fmaf(sv, Wv1[k*E_ + lane], vacc);
    }
    spb_l[lane] = sacc;
    float pv = fmaxf(vacc, 0.f) * Wv2[lane];
    #pragma unroll
    for (int off = 32; off >= 1; off >>= 1) pv += __shfl_xor(pv, off, 64);
    if (lane == 0) v_l = pv + bv2[0];
  }

  // --- lane-parallel sort: lane = (si = lane>>3, j = lane&7)
  // counter mapping identical to R3 (bit-exact verified)
  {
    const unsigned k1 = (unsigned)rng[0];
    unsigned cnt = ((unsigned)(bt*SS_ + w + 4*(lane >> 3)) << 3) + (unsigned)(lane & 7);
    unsigned o0, o1;
    threefry2x32(0u, k1, 0u, cnt, o0, o1);
    const unsigned comp = (((o0 ^ o1) >> 9) << 3) | (unsigned)(lane & 7); // distinct keys
    int rank = 0;
    #pragma unroll
    for (int d = 1; d < 8; ++d) {
      unsigned oc = (unsigned)__shfl_xor((int)comp, d, 8);
      rank += (oc < comp) ? 1 : 0;
    }
    gmap_l[w*64 + (lane >> 3)*8 + rank] = (unsigned char)(lane & 7);
  }

  __syncthreads();

  // --- B fragments: W2^T rows -> regs.  B[k][n]: lane holds B[kt*32+(l>>4)*8+j][l&15]
  bf16x8 bfr[2][4];
  #pragma unroll
  for (int kt = 0; kt < 2; ++kt)
    #pragma unroll
    for (int nt = 0; nt < 4; ++nt) {
      const int n = nt*16 + (lane & 15);
      const int byte = (n*128 + (kt*32 + (lane >> 4)*8)*2) ^ ((n & 7) << 4);
      bfr[kt][nt] = *reinterpret_cast<const bf16x8*>(&w2_l[byte >> 1]);
    }

  const float spb = spb_l[lane];

  // --- layer 1 (fp32 prefix) -> h1 rows to LDS as bf16 (swizzled)
  const int hbase = w*4096;
  #pragma unroll
  for (int si = 0; si < 8; ++si) {
    const uint2 gm = *reinterpret_cast<const uint2*>(&gmap_l[w*64 + si*8]);
    float acc = 0.f;
    #pragma unroll
    for (int p = 0; p < 8; ++p) {
      const unsigned g = ((p < 4 ? (gm.x >> (8*p)) : (gm.y >> (8*(p - 4)))) & 0xffu);
      acc += c_l[((p << 3) + (int)g)*E_ + lane];
      const float h1 = fmaxf(acc + spb, 0.f);
      const int r = (si << 3) + p;
      const int byte = ((r << 7) + (lane << 1)) ^ ((r & 7) << 4);
      h1_l[hbase + (byte >> 1)] = (__bf16)h1;
    }
  }

  __syncthreads();   // lgkmcnt drain: h1 writes (by other lanes) visible to frag reads

  // --- A fragments: A[m][k]: lane holds A[mt*16+(l&15)][kt*32+(l>>4)*8+j]
  bf16x8 afr[4][2];
  #pragma unroll
  for (int mt = 0; mt < 4; ++mt)
    #pragma unroll
    for (int kt = 0; kt < 2; ++kt) {
      const int row = mt*16 + (lane & 15);
      const int byte = ((row << 7) + (kt*32 + (lane >> 4)*8)*2) ^ ((row & 7) << 4);
      afr[mt][kt] = *reinterpret_cast<const bf16x8*>(&h1_l[hbase + (byte >> 1)]);
    }

  // --- 64x64x64 GEMM: 32 MFMAs, fp32 accumulate
  f32x4 acc4[4][4];
  #pragma unroll
  for (int mt = 0; mt < 4; ++mt)
    #pragma unroll
    for (int nt = 0; nt < 4; ++nt)
      acc4[mt][nt] = (f32x4){0.f, 0.f, 0.f, 0.f};
  #pragma unroll
  for (int mt = 0; mt < 4; ++mt)
    #pragma unroll
    for (int nt = 0; nt < 4; ++nt) {
      acc4[mt][nt] = __builtin_amdgcn_mfma_f32_16x16x32_bf16(afr[mt][0], bfr[0][nt], acc4[mt][nt], 0, 0, 0);
      acc4[mt][nt] = __builtin_amdgcn_mfma_f32_16x16x32_bf16(afr[mt][1], bfr[1][nt], acc4[mt][nt], 0, 0, 0);
    }

  // --- epilogue: h2=relu(D+b2); rowsum over n of h2*Wa; route to (sample,agent)
  float b2r[4], war[4];
  #pragma unroll
  for (int nt = 0; nt < 4; ++nt) {
    b2r[nt] = b2[nt*16 + (lane & 15)];
    war[nt] = Wa[nt*16 + (lane & 15)];
  }
  #pragma unroll
  for (int mt = 0; mt < 4; ++mt)
    #pragma unroll
    for (int reg = 0; reg < 4; ++reg) {
      float partv = 0.f;
      #pragma unroll
      for (int nt = 0; nt < 4; ++nt)
        partv = fmaf(fmaxf(acc4[mt][nt][reg] + b2r[nt], 0.f), war[nt], partv);
      // reduce across the 16 lanes of this row (D: col=lane&15)
      partv += __shfl_xor(partv, 1, 16);
      partv += __shfl_xor(partv, 2, 16);
      partv += __shfl_xor(partv, 4, 16);
      partv += __shfl_xor(partv, 8, 16);
      if ((lane & 15) == 0) {
        const int r = mt*16 + (lane >> 4)*4 + reg;   // D: row=(lane>>4)*4+reg
        const int g = gmap_l[w*64 + r];              // r = s*8+p -> agent
        contrib_l[w*64 + (r >> 3)*8 + g] = partv;    // unique (w,s,g)
      }
    }

  __syncthreads();

  // --- final: mean over 32 (w,s) per agent + value head
  if (w == 0) {
    float s = contrib_l[lane] + contrib_l[lane + 64]
            + contrib_l[lane + 128] + contrib_l[lane + 192];
    s += __shfl_xor(s, 8, 64);
    s += __shfl_xor(s, 16, 64);
    s += __shfl_xor(s, 32, 64);
    if (lane < N_) out[bt*N_ + lane] = s*(1.f/SS_) + v_l + ba[0];
  }
}

extern "C" void kernel_launch(void* const* d_in, const int* in_sizes, int n_in,
                              void* d_out, int out_size, void* d_ws, size_t ws_size,
                              hipStream_t stream) {
  const float* states   = (const float*)d_in[0];
  const float* agent_qs = (const float*)d_in[1];
  const float* W1  = (const float*)d_in[2];
  const float* b1  = (const float*)d_in[3];
  const float* W2  = (const float*)d_in[4];
  const float* b2  = (const float*)d_in[5];
  const float* Wa  = (const float*)d_in[6];
  const float* ba  = (const float*)d_in[7];
  const float* Wv1 = (const float*)d_in[8];
  const float* bv1 = (const float*)d_in[9];
  const float* Wv2 = (const float*)d_in[10];
  const float* bv2 = (const float*)d_in[11];
  const int*   rng = (const int*)d_in[12];
  float* out = (float*)d_out;

  hipLaunchKernelGGL(shapley_kernel, dim3(BT_), dim3(256), 0, stream,
                     states, agent_qs, W1, b1, W2, b2, Wa, ba, Wv1, bv1, Wv2, bv2,
                     rng, out);
}

// Round 6
// 21.070 us; speedup vs baseline: 13.8930x; 1.4266x over previous
//
// R6 = R5 kernel resubmitted verbatim (R5 died to UnresponsiveContainer before
// any measurement; no data to act on — same policy as R2->R3).
#include <hip/hip_runtime.h>

typedef __bf16 bf16x8 __attribute__((ext_vector_type(8)));
typedef float  f32x4  __attribute__((ext_vector_type(4)));

#define S_ 128
#define N_ 8
#define A_ 10
#define E_ 64
#define SS_ 32
#define BT_ 1024

__device__ __forceinline__ unsigned rotl32(unsigned v, int n){ return (v<<n)|(v>>(32-n)); }

// Threefry-2x32, 20 rounds, standard JAX constants. (Bit-exact, verified R1/R3/R4.)
__device__ __forceinline__ void threefry2x32(unsigned k0, unsigned k1,
                                             unsigned x0, unsigned x1,
                                             unsigned &o0, unsigned &o1){
  const unsigned ks2 = k0 ^ k1 ^ 0x1BD11BDAu;
  x0 += k0; x1 += k1;
  x0+=x1; x1=rotl32(x1,13); x1^=x0;
  x0+=x1; x1=rotl32(x1,15); x1^=x0;
  x0+=x1; x1=rotl32(x1,26); x1^=x0;
  x0+=x1; x1=rotl32(x1, 6); x1^=x0;
  x0+=k1; x1+=ks2+1u;
  x0+=x1; x1=rotl32(x1,17); x1^=x0;
  x0+=x1; x1=rotl32(x1,29); x1^=x0;
  x0+=x1; x1=rotl32(x1,16); x1^=x0;
  x0+=x1; x1=rotl32(x1,24); x1^=x0;
  x0+=ks2; x1+=k0+2u;
  x0+=x1; x1=rotl32(x1,13); x1^=x0;
  x0+=x1; x1=rotl32(x1,15); x1^=x0;
  x0+=x1; x1=rotl32(x1,26); x1^=x0;
  x0+=x1; x1=rotl32(x1, 6); x1^=x0;
  x0+=k0; x1+=k1+3u;
  x0+=x1; x1=rotl32(x1,17); x1^=x0;
  x0+=x1; x1=rotl32(x1,29); x1^=x0;
  x0+=x1; x1=rotl32(x1,16); x1^=x0;
  x0+=x1; x1=rotl32(x1,24); x1^=x0;
  x0+=k1; x1+=ks2+4u;
  x0+=x1; x1=rotl32(x1,13); x1^=x0;
  x0+=x1; x1=rotl32(x1,15); x1^=x0;
  x0+=x1; x1=rotl32(x1,26); x1^=x0;
  x0+=x1; x1=rotl32(x1, 6); x1^=x0;
  x0+=ks2; x1+=k0+5u;
  o0=x0; o1=x1;
}

__global__ __launch_bounds__(256, 4) void shapley_kernel(
    const float* __restrict__ states,    // (BT,128)
    const float* __restrict__ agent_qs,  // (BT,A=10,N=8)
    const float* __restrict__ W1,        // (208,64)
    const float* __restrict__ b1,        // (64)
    const float* __restrict__ W2,        // (64,64)
    const float* __restrict__ b2,        // (64)
    const float* __restrict__ Wa,        // (64,1)
    const float* __restrict__ ba,        // (1)
    const float* __restrict__ Wv1,       // (128,64)
    const float* __restrict__ bv1,       // (64)
    const float* __restrict__ Wv2,       // (64,1)
    const float* __restrict__ bv2,       // (1)
    const int*   __restrict__ rng,       // (1)
    float* __restrict__ out)             // (BT,8)
{
  __shared__ float   c_l[N_*N_*E_];        // 16 KB fp32 c[p][g][e]
  __shared__ __bf16  h1_l[4*2048];         // 16 KB: per-wave 4KB (32 rows);
                                           //   bytes 0..8191 overlaid with W2^T at staging
  __shared__ float   sp_part[2][E_];       // state-proj partials
  __shared__ float   vp_part[2][E_];       // value-proj partials
  __shared__ unsigned char gmap_l[4*64];   // [wave][sample][pos] -> agent
  __shared__ float   contrib_l[4*64];      // [wave][sample][agent]

  const int bt   = blockIdx.x;
  const int tid  = threadIdx.x;
  const int w    = tid >> 6;
  const int lane = tid & 63;

  // ================= staging phase (everything before sync1) =================

  // c-table: c[p][g][lane] = sum_a aq[a,g] * W1q[p,a,lane]  (fp32, exact)
  {
    const float* aqb = agent_qs + bt*(A_*N_);
    #pragma unroll
    for (int i = 0; i < 16; ++i) {
      const int combo = w*16 + i;
      const int p = combo >> 3, g = combo & 7;
      float acc = 0.f;
      #pragma unroll
      for (int a = 0; a < A_; ++a)
        acc = fmaf(aqb[a*N_ + g], W1[(S_ + p*A_ + a)*E_ + lane], acc);
      c_l[combo*E_ + lane] = acc;
    }
  }

  // W2 -> bf16, transposed [n][k], XOR-swizzled, into the h1 overlay region
  {
    const int f = lane;                   // output channel n (row of overlay)
    #pragma unroll
    for (int i = 0; i < 16; ++i) {
      const int e = w + 4*i;              // input channel k
      const int byte = (f*128 + e*2) ^ ((f & 7) << 4);
      h1_l[byte >> 1] = (__bf16)W2[e*E_ + f];
    }
  }

  // state + value projections, split across the 4 waves (64-iter chains)
  {
    const float* st = states + bt*S_;
    float acc;
    if (w == 0) {
      acc = b1[lane];
      #pragma unroll 8
      for (int k = 0; k < 64; ++k) acc = fmaf(st[k], W1[k*E_ + lane], acc);
      sp_part[0][lane] = acc;
    } else if (w == 1) {
      acc = 0.f;
      #pragma unroll 8
      for (int k = 64; k < 128; ++k) acc = fmaf(st[k], W1[k*E_ + lane], acc);
      sp_part[1][lane] = acc;
    } else if (w == 2) {
      acc = bv1[lane];
      #pragma unroll 8
      for (int k = 0; k < 64; ++k) acc = fmaf(st[k], Wv1[k*E_ + lane], acc);
      vp_part[0][lane] = acc;
    } else {
      acc = 0.f;
      #pragma unroll 8
      for (int k = 64; k < 128; ++k) acc = fmaf(st[k], Wv1[k*E_ + lane], acc);
      vp_part[1][lane] = acc;
    }
  }

  // wave-0 tail constants
  float wv2r = 0.f, tailc = 0.f;
  if (w == 0) { wv2r = Wv2[lane]; tailc = ba[0] + bv2[0]; }

  // epilogue constants (all waves)
  float b2r[4], war[4];
  #pragma unroll
  for (int nt = 0; nt < 4; ++nt) {
    b2r[nt] = b2[nt*16 + (lane & 15)];
    war[nt] = Wa[nt*16 + (lane & 15)];
  }

  // lane-parallel sort: lane = (si = lane>>3, j = lane&7)   [verbatim R4]
  {
    const unsigned k1 = (unsigned)rng[0];
    unsigned cnt = ((unsigned)(bt*SS_ + w + 4*(lane >> 3)) << 3) + (unsigned)(lane & 7);
    unsigned o0, o1;
    threefry2x32(0u, k1, 0u, cnt, o0, o1);
    const unsigned comp = (((o0 ^ o1) >> 9) << 3) | (unsigned)(lane & 7);
    int rank = 0;
    #pragma unroll
    for (int d = 1; d < 8; ++d) {
      unsigned oc = (unsigned)__shfl_xor((int)comp, d, 8);
      rank += (oc < comp) ? 1 : 0;
    }
    gmap_l[w*64 + (lane >> 3)*8 + rank] = (unsigned char)(lane & 7);
  }

  __syncthreads();   // sync1: c_l, overlay W2, partials, gmap all visible

  // B fragments from overlay: B[k][n], lane holds B[kt*32+(l>>4)*8+j][l&15]
  bf16x8 bfr[2][4];
  #pragma unroll
  for (int kt = 0; kt < 2; ++kt)
    #pragma unroll
    for (int nt = 0; nt < 4; ++nt) {
      const int n = nt*16 + (lane & 15);
      const int byte = (n*128 + (kt*32 + (lane >> 4)*8)*2) ^ ((n & 7) << 4);
      bfr[kt][nt] = *reinterpret_cast<const bf16x8*>(&h1_l[byte >> 1]);
    }

  const float spb = sp_part[0][lane] + sp_part[1][lane];

  __syncthreads();   // sync2: all B-frag reads done before h1 overwrites overlay

  const int wbase = w*4096;   // byte base of this wave's h1 region

  #pragma unroll
  for (int pp = 0; pp < 2; ++pp) {
    // --- layer 1 (fp32 prefix) -> 32 h1 rows (samples pp*4..pp*4+3), bf16 swizzled
    #pragma unroll
    for (int si2 = 0; si2 < 4; ++si2) {
      const int si = pp*4 + si2;
      const uint2 gm = *reinterpret_cast<const uint2*>(&gmap_l[w*64 + si*8]);
      float acc = 0.f;
      #pragma unroll
      for (int p = 0; p < 8; ++p) {
        const unsigned g = ((p < 4 ? (gm.x >> (8*p)) : (gm.y >> (8*(p - 4)))) & 0xffu);
        acc += c_l[((p << 3) + (int)g)*E_ + lane];
        const float h1 = fmaxf(acc + spb, 0.f);
        const int r2 = (si2 << 3) + p;
        const int byte = ((r2 << 7) + (lane << 1)) ^ ((r2 & 7) << 4);
        h1_l[(wbase + byte) >> 1] = (__bf16)h1;
      }
    }

    // same-wave LDS write->read ordering (no cross-wave barrier needed)
    asm volatile("s_waitcnt lgkmcnt(0)" ::: "memory");
    __builtin_amdgcn_sched_barrier(0);

    // --- A fragments: lane holds A[mt2*16+(l&15)][kt*32+(l>>4)*8+j]
    bf16x8 afr[2][2];
    #pragma unroll
    for (int mt2 = 0; mt2 < 2; ++mt2)
      #pragma unroll
      for (int kt = 0; kt < 2; ++kt) {
        const int lr = mt2*16 + (lane & 15);
        const int byte = ((lr << 7) + (kt*32 + (lane >> 4)*8)*2) ^ ((lr & 7) << 4);
        afr[mt2][kt] = *reinterpret_cast<const bf16x8*>(&h1_l[(wbase + byte) >> 1]);
      }

    // --- 32x64x64 GEMM: 16 MFMAs, fp32 accumulate
    f32x4 acc4[2][4];
    #pragma unroll
    for (int mt2 = 0; mt2 < 2; ++mt2)
      #pragma unroll
      for (int nt = 0; nt < 4; ++nt) {
        acc4[mt2][nt] = (f32x4){0.f, 0.f, 0.f, 0.f};
        acc4[mt2][nt] = __builtin_amdgcn_mfma_f32_16x16x32_bf16(afr[mt2][0], bfr[0][nt], acc4[mt2][nt], 0, 0, 0);
        acc4[mt2][nt] = __builtin_amdgcn_mfma_f32_16x16x32_bf16(afr[mt2][1], bfr[1][nt], acc4[mt2][nt], 0, 0, 0);
      }

    // --- epilogue: h2=relu(D+b2); rowsum of h2*Wa; route to (sample,agent)
    #pragma unroll
    for (int mt2 = 0; mt2 < 2; ++mt2)
      #pragma unroll
      for (int reg = 0; reg < 4; ++reg) {
        float partv = 0.f;
        #pragma unroll
        for (int nt = 0; nt < 4; ++nt)
          partv = fmaf(fmaxf(acc4[mt2][nt][reg] + b2r[nt], 0.f), war[nt], partv);
        partv += __shfl_xor(partv, 1, 16);
        partv += __shfl_xor(partv, 2, 16);
        partv += __shfl_xor(partv, 4, 16);
        partv += __shfl_xor(partv, 8, 16);
        if ((lane & 15) == 0) {
          const int r2 = mt2*16 + (lane >> 4)*4 + reg;   // D: row=(lane>>4)*4+reg
          const int r  = pp*32 + r2;                     // global row = s*8+p
          const int g  = gmap_l[w*64 + r];
          contrib_l[w*64 + (r >> 3)*8 + g] = partv;      // unique (w,s,g)
        }
      }

    // pass-1 h1 writes may not overtake pass-0 A-frag reads (same-wave DS order);
    // extra safety drain before overwriting:
    asm volatile("s_waitcnt lgkmcnt(0)" ::: "memory");
    __builtin_amdgcn_sched_barrier(0);
  }

  __syncthreads();

  // --- final: mean over 32 (w,s) per agent + value head (wave 0)
  if (w == 0) {
    float s = contrib_l[lane] + contrib_l[lane + 64]
            + contrib_l[lane + 128] + contrib_l[lane + 192];
    s += __shfl_xor(s, 8, 64);
    s += __shfl_xor(s, 16, 64);
    s += __shfl_xor(s, 32, 64);
    float pv = fmaxf(vp_part[0][lane] + vp_part[1][lane], 0.f) * wv2r;
    #pragma unroll
    for (int off = 32; off >= 1; off >>= 1) pv += __shfl_xor(pv, off, 64);
    if (lane < N_) out[bt*N_ + lane] = s*(1.f/SS_) + pv + tailc;
  }
}

extern "C" void kernel_launch(void* const* d_in, const int* in_sizes, int n_in,
                              void* d_out, int out_size, void* d_ws, size_t ws_size,
                              hipStream_t stream) {
  const float* states   = (const float*)d_in[0];
  const float* agent_qs = (const float*)d_in[1];
  const float* W1  = (const float*)d_in[2];
  const float* b1  = (const float*)d_in[3];
  const float* W2  = (const float*)d_in[4];
  const float* b2  = (const float*)d_in[5];
  const float* Wa  = (const float*)d_in[6];
  const float* ba  = (const float*)d_in[7];
  const float* Wv1 = (const float*)d_in[8];
  const float* bv1 = (const float*)d_in[9];
  const float* Wv2 = (const float*)d_in[10];
  const float* bv2 = (const float*)d_in[11];
  const int*   rng = (const int*)d_in[12];
  float* out = (float*)d_out;

  hipLaunchKernelGGL(shapley_kernel, dim3(BT_), dim3(256), 0, stream,
                     states, agent_qs, W1, b1, W2, b2, Wa, ba, Wv1, bv1, Wv2, bv2,
                     rng, out);
}

// Round 7
// 19.073 us; speedup vs baseline: 15.3477x; 1.1047x over previous
//
// R7: staging-latency surgery. R6 (21.1us): per-block critical path = ~250 scalar
// VMEM loads/thread on cold L2 (harness fills evict caches between replays) +
// 64-deep proj chains. Changes: c-table 160->20 loads (acc[16] regs, uniform-float4
// aq via s_load), 4-way wave split of projections (chain 32), dwordx4 W2 staging.
// Sort/prefix/GEMM/epilogue verbatim R6 (absmax 2e-3, bit-exact PRNG).
#include <hip/hip_runtime.h>

typedef __bf16 bf16x8 __attribute__((ext_vector_type(8)));
typedef float  f32x4  __attribute__((ext_vector_type(4)));

#define S_ 128
#define N_ 8
#define A_ 10
#define E_ 64
#define SS_ 32
#define BT_ 1024

__device__ __forceinline__ unsigned rotl32(unsigned v, int n){ return (v<<n)|(v>>(32-n)); }

// Threefry-2x32, 20 rounds, standard JAX constants. (Bit-exact, verified R1/R3/R4/R6.)
__device__ __forceinline__ void threefry2x32(unsigned k0, unsigned k1,
                                             unsigned x0, unsigned x1,
                                             unsigned &o0, unsigned &o1){
  const unsigned ks2 = k0 ^ k1 ^ 0x1BD11BDAu;
  x0 += k0; x1 += k1;
  x0+=x1; x1=rotl32(x1,13); x1^=x0;
  x0+=x1; x1=rotl32(x1,15); x1^=x0;
  x0+=x1; x1=rotl32(x1,26); x1^=x0;
  x0+=x1; x1=rotl32(x1, 6); x1^=x0;
  x0+=k1; x1+=ks2+1u;
  x0+=x1; x1=rotl32(x1,17); x1^=x0;
  x0+=x1; x1=rotl32(x1,29); x1^=x0;
  x0+=x1; x1=rotl32(x1,16); x1^=x0;
  x0+=x1; x1=rotl32(x1,24); x1^=x0;
  x0+=ks2; x1+=k0+2u;
  x0+=x1; x1=rotl32(x1,13); x1^=x0;
  x0+=x1; x1=rotl32(x1,15); x1^=x0;
  x0+=x1; x1=rotl32(x1,26); x1^=x0;
  x0+=x1; x1=rotl32(x1, 6); x1^=x0;
  x0+=k0; x1+=k1+3u;
  x0+=x1; x1=rotl32(x1,17); x1^=x0;
  x0+=x1; x1=rotl32(x1,29); x1^=x0;
  x0+=x1; x1=rotl32(x1,16); x1^=x0;
  x0+=x1; x1=rotl32(x1,24); x1^=x0;
  x0+=k1; x1+=ks2+4u;
  x0+=x1; x1=rotl32(x1,13); x1^=x0;
  x0+=x1; x1=rotl32(x1,15); x1^=x0;
  x0+=x1; x1=rotl32(x1,26); x1^=x0;
  x0+=x1; x1=rotl32(x1, 6); x1^=x0;
  x0+=ks2; x1+=k0+5u;
  o0=x0; o1=x1;
}

__global__ __launch_bounds__(256, 4) void shapley_kernel(
    const float* __restrict__ states,    // (BT,128)
    const float* __restrict__ agent_qs,  // (BT,A=10,N=8)
    const float* __restrict__ W1,        // (208,64)
    const float* __restrict__ b1,        // (64)
    const float* __restrict__ W2,        // (64,64)
    const float* __restrict__ b2,        // (64)
    const float* __restrict__ Wa,        // (64,1)
    const float* __restrict__ ba,        // (1)
    const float* __restrict__ Wv1,       // (128,64)
    const float* __restrict__ bv1,       // (64)
    const float* __restrict__ Wv2,       // (64,1)
    const float* __restrict__ bv2,       // (1)
    const int*   __restrict__ rng,       // (1)
    float* __restrict__ out)             // (BT,8)
{
  __shared__ float   c_l[N_*N_*E_];        // 16 KB fp32 c[p][g][e]
  __shared__ __bf16  h1_l[4*2048];         // 16 KB: per-wave 4KB (32 rows);
                                           //   bytes 0..8191 overlaid with W2^T at staging
  __shared__ float   sp_part[4][E_];       // state-proj partials (4-way k-split)
  __shared__ float   vp_part[4][E_];       // value-proj partials
  __shared__ unsigned char gmap_l[4*64];   // [wave][sample][pos] -> agent
  __shared__ float   contrib_l[4*64];      // [wave][sample][agent]

  const int bt   = blockIdx.x;
  const int tid  = threadIdx.x;
  const int w    = tid >> 6;
  const int lane = tid & 63;

  // ================= staging phase (everything before sync1) =================

  // --- c-table: c[p][g][e] = sum_a aq[a,g] * W1q[p,a,e]  (fp32, exact).
  // This wave owns p0=2w, p1=2w+1; acc[(i<<3)|g] in regs; aq rows via uniform
  // float4 (scalarized to s_load); 2 coalesced W1q loads per a (20 total).
  {
    const float* aqb = agent_qs + bt*(A_*N_);
    const float* w1q = W1 + (S_ + 2*w*A_)*E_ + lane;
    float acc[16];
    #pragma unroll
    for (int j = 0; j < 16; ++j) acc[j] = 0.f;
    #pragma unroll
    for (int a = 0; a < A_; ++a) {
      const float4 aq0 = *reinterpret_cast<const float4*>(aqb + a*N_);
      const float4 aq1 = *reinterpret_cast<const float4*>(aqb + a*N_ + 4);
      const float w1q0 = w1q[a*E_];
      const float w1q1 = w1q[(A_ + a)*E_];
      acc[0] = fmaf(aq0.x, w1q0, acc[0]);  acc[1] = fmaf(aq0.y, w1q0, acc[1]);
      acc[2] = fmaf(aq0.z, w1q0, acc[2]);  acc[3] = fmaf(aq0.w, w1q0, acc[3]);
      acc[4] = fmaf(aq1.x, w1q0, acc[4]);  acc[5] = fmaf(aq1.y, w1q0, acc[5]);
      acc[6] = fmaf(aq1.z, w1q0, acc[6]);  acc[7] = fmaf(aq1.w, w1q0, acc[7]);
      acc[8]  = fmaf(aq0.x, w1q1, acc[8]);   acc[9]  = fmaf(aq0.y, w1q1, acc[9]);
      acc[10] = fmaf(aq0.z, w1q1, acc[10]);  acc[11] = fmaf(aq0.w, w1q1, acc[11]);
      acc[12] = fmaf(aq1.x, w1q1, acc[12]);  acc[13] = fmaf(aq1.y, w1q1, acc[13]);
      acc[14] = fmaf(aq1.z, w1q1, acc[14]);  acc[15] = fmaf(aq1.w, w1q1, acc[15]);
    }
    #pragma unroll
    for (int j = 0; j < 16; ++j)
      c_l[((2*w)*N_ + j)*E_ + lane] = acc[j];   // j = (i<<3)|g -> combo 16w+j
  }

  // --- W2 -> bf16, transposed [n][k], XOR-swizzled, into the h1 overlay region.
  // dwordx4 reads: thread (erow=tid>>4, fgrp=tid&15) loads W2[e][4f..4f+3].
  {
    const int f0   = (tid & 15) * 4;
    const int erow = tid >> 4;
    #pragma unroll
    for (int i = 0; i < 4; ++i) {
      const int e = erow + 16*i;
      const float4 wv = *reinterpret_cast<const float4*>(W2 + e*E_ + f0);
      #pragma unroll
      for (int q = 0; q < 4; ++q) {
        const int f = f0 + q;
        const int byte = (f*128 + e*2) ^ ((f & 7) << 4);
        h1_l[byte >> 1] = (__bf16)((q == 0) ? wv.x : (q == 1) ? wv.y : (q == 2) ? wv.z : wv.w);
      }
    }
  }

  // --- state + value projections: 4-way k-split across waves (32-deep chains)
  {
    const float* st = states + bt*S_;
    const int k0 = w*32;
    float sacc = (w == 0) ? b1[lane]  : 0.f;
    float vacc = (w == 0) ? bv1[lane] : 0.f;
    #pragma unroll 8
    for (int k = k0; k < k0 + 32; ++k) {
      const float sv = st[k];                       // uniform -> s_load
      sacc = fmaf(sv, W1 [k*E_ + lane], sacc);
      vacc = fmaf(sv, Wv1[k*E_ + lane], vacc);
    }
    sp_part[w][lane] = sacc;
    vp_part[w][lane] = vacc;
  }

  // wave-0 tail constants
  float wv2r = 0.f, tailc = 0.f;
  if (w == 0) { wv2r = Wv2[lane]; tailc = ba[0] + bv2[0]; }

  // epilogue constants (all waves)
  float b2r[4], war[4];
  #pragma unroll
  for (int nt = 0; nt < 4; ++nt) {
    b2r[nt] = b2[nt*16 + (lane & 15)];
    war[nt] = Wa[nt*16 + (lane & 15)];
  }

  // lane-parallel sort: lane = (si = lane>>3, j = lane&7)   [verbatim R4/R6]
  {
    const unsigned k1 = (unsigned)rng[0];
    unsigned cnt = ((unsigned)(bt*SS_ + w + 4*(lane >> 3)) << 3) + (unsigned)(lane & 7);
    unsigned o0, o1;
    threefry2x32(0u, k1, 0u, cnt, o0, o1);
    const unsigned comp = (((o0 ^ o1) >> 9) << 3) | (unsigned)(lane & 7);
    int rank = 0;
    #pragma unroll
    for (int d = 1; d < 8; ++d) {
      unsigned oc = (unsigned)__shfl_xor((int)comp, d, 8);
      rank += (oc < comp) ? 1 : 0;
    }
    gmap_l[w*64 + (lane >> 3)*8 + rank] = (unsigned char)(lane & 7);
  }

  __syncthreads();   // sync1: c_l, overlay W2, partials, gmap all visible

  // B fragments from overlay: B[k][n], lane holds B[kt*32+(l>>4)*8+j][l&15]
  bf16x8 bfr[2][4];
  #pragma unroll
  for (int kt = 0; kt < 2; ++kt)
    #pragma unroll
    for (int nt = 0; nt < 4; ++nt) {
      const int n = nt*16 + (lane & 15);
      const int byte = (n*128 + (kt*32 + (lane >> 4)*8)*2) ^ ((n & 7) << 4);
      bfr[kt][nt] = *reinterpret_cast<const bf16x8*>(&h1_l[byte >> 1]);
    }

  const float spb = (sp_part[0][lane] + sp_part[1][lane])
                  + (sp_part[2][lane] + sp_part[3][lane]);

  __syncthreads();   // sync2: all B-frag reads done before h1 overwrites overlay

  const int wbase = w*4096;   // byte base of this wave's h1 region

  #pragma unroll
  for (int pp = 0; pp < 2; ++pp) {
    // --- layer 1 (fp32 prefix) -> 32 h1 rows (samples pp*4..pp*4+3), bf16 swizzled
    #pragma unroll
    for (int si2 = 0; si2 < 4; ++si2) {
      const int si = pp*4 + si2;
      const uint2 gm = *reinterpret_cast<const uint2*>(&gmap_l[w*64 + si*8]);
      float acc = 0.f;
      #pragma unroll
      for (int p = 0; p < 8; ++p) {
        const unsigned g = ((p < 4 ? (gm.x >> (8*p)) : (gm.y >> (8*(p - 4)))) & 0xffu);
        acc += c_l[((p << 3) + (int)g)*E_ + lane];
        const float h1 = fmaxf(acc + spb, 0.f);
        const int r2 = (si2 << 3) + p;
        const int byte = ((r2 << 7) + (lane << 1)) ^ ((r2 & 7) << 4);
        h1_l[(wbase + byte) >> 1] = (__bf16)h1;
      }
    }

    // same-wave LDS write->read ordering (no cross-wave barrier needed)
    asm volatile("s_waitcnt lgkmcnt(0)" ::: "memory");
    __builtin_amdgcn_sched_barrier(0);

    // --- A fragments: lane holds A[mt2*16+(l&15)][kt*32+(l>>4)*8+j]
    bf16x8 afr[2][2];
    #pragma unroll
    for (int mt2 = 0; mt2 < 2; ++mt2)
      #pragma unroll
      for (int kt = 0; kt < 2; ++kt) {
        const int lr = mt2*16 + (lane & 15);
        const int byte = ((lr << 7) + (kt*32 + (lane >> 4)*8)*2) ^ ((lr & 7) << 4);
        afr[mt2][kt] = *reinterpret_cast<const bf16x8*>(&h1_l[(wbase + byte) >> 1]);
      }

    // --- 32x64x64 GEMM: 16 MFMAs, fp32 accumulate
    f32x4 acc4[2][4];
    #pragma unroll
    for (int mt2 = 0; mt2 < 2; ++mt2)
      #pragma unroll
      for (int nt = 0; nt < 4; ++nt) {
        acc4[mt2][nt] = (f32x4){0.f, 0.f, 0.f, 0.f};
        acc4[mt2][nt] = __builtin_amdgcn_mfma_f32_16x16x32_bf16(afr[mt2][0], bfr[0][nt], acc4[mt2][nt], 0, 0, 0);
        acc4[mt2][nt] = __builtin_amdgcn_mfma_f32_16x16x32_bf16(afr[mt2][1], bfr[1][nt], acc4[mt2][nt], 0, 0, 0);
      }

    // --- epilogue: h2=relu(D+b2); rowsum of h2*Wa; route to (sample,agent)
    #pragma unroll
    for (int mt2 = 0; mt2 < 2; ++mt2)
      #pragma unroll
      for (int reg = 0; reg < 4; ++reg) {
        float partv = 0.f;
        #pragma unroll
        for (int nt = 0; nt < 4; ++nt)
          partv = fmaf(fmaxf(acc4[mt2][nt][reg] + b2r[nt], 0.f), war[nt], partv);
        partv += __shfl_xor(partv, 1, 16);
        partv += __shfl_xor(partv, 2, 16);
        partv += __shfl_xor(partv, 4, 16);
        partv += __shfl_xor(partv, 8, 16);
        if ((lane & 15) == 0) {
          const int r2 = mt2*16 + (lane >> 4)*4 + reg;   // D: row=(lane>>4)*4+reg
          const int r  = pp*32 + r2;                     // global row = s*8+p
          const int g  = gmap_l[w*64 + r];
          contrib_l[w*64 + (r >> 3)*8 + g] = partv;      // unique (w,s,g)
        }
      }

    // pass-1 h1 writes may not overtake pass-0 A-frag reads:
    asm volatile("s_waitcnt lgkmcnt(0)" ::: "memory");
    __builtin_amdgcn_sched_barrier(0);
  }

  __syncthreads();

  // --- final: mean over 32 (w,s) per agent + value head (wave 0)
  if (w == 0) {
    float s = contrib_l[lane] + contrib_l[lane + 64]
            + contrib_l[lane + 128] + contrib_l[lane + 192];
    s += __shfl_xor(s, 8, 64);
    s += __shfl_xor(s, 16, 64);
    s += __shfl_xor(s, 32, 64);
    float pv = fmaxf((vp_part[0][lane] + vp_part[1][lane])
                   + (vp_part[2][lane] + vp_part[3][lane]), 0.f) * wv2r;
    #pragma unroll
    for (int off = 32; off >= 1; off >>= 1) pv += __shfl_xor(pv, off, 64);
    if (lane < N_) out[bt*N_ + lane] = s*(1.f/SS_) + pv + tailc;
  }
}

extern "C" void kernel_launch(void* const* d_in, const int* in_sizes, int n_in,
                              void* d_out, int out_size, void* d_ws, size_t ws_size,
                              hipStream_t stream) {
  const float* states   = (const float*)d_in[0];
  const float* agent_qs = (const float*)d_in[1];
  const float* W1  = (const float*)d_in[2];
  const float* b1  = (const float*)d_in[3];
  const float* W2  = (const float*)d_in[4];
  const float* b2  = (const float*)d_in[5];
  const float* Wa  = (const float*)d_in[6];
  const float* ba  = (const float*)d_in[7];
  const float* Wv1 = (const float*)d_in[8];
  const float* bv1 = (const float*)d_in[9];
  const float* Wv2 = (const float*)d_in[10];
  const float* bv2 = (const float*)d_in[11];
  const int*   rng = (const int*)d_in[12];
  float* out = (float*)d_out;

  hipLaunchKernelGGL(shapley_kernel, dim3(BT_), dim3(256), 0, stream,
                     states, agent_qs, W1, b1, W2, b2, Wa, ba, Wv1, bv1, Wv2, bv2,
                     rng, out);
}